// Round 12
// baseline (627.117 us; speedup 1.0000x reference)
//
#include <hip/hip_runtime.h>
#include <hip/hip_fp16.h>
#include <hip/hip_cooperative_groups.h>

namespace cg = cooperative_groups;

#define D 64

// ===========================================================================
// PATH A: single cooperative kernel (phases separated by grid.sync()).
// Grid-stride everywhere -> correct at ANY grid size.
// ===========================================================================
__global__ __launch_bounds__(256, 4) void fused_graphconv_kernel(
    const float*  __restrict__ x,
    const float*  __restrict__ edge_val,
    const float*  __restrict__ W,
    const int*    __restrict__ edge_src,
    const int*    __restrict__ edge_dst,
    int*    __restrict__ counts,
    int*    __restrict__ offsets,
    int*    __restrict__ cursor,
    int*    __restrict__ chunkSum,
    int2*   __restrict__ sorted_sv,
    __half* __restrict__ xh,
    float*  __restrict__ out,
    int nNodes, int nEdges)
{
    cg::grid_group grid = cg::this_grid();

    __shared__ float Wt[D][D + 4];   // Wt[j][k] = W[k][j]
    __shared__ float accL[4][D];     // per-wave acc staging
    __shared__ int   sbuf[256];      // scan/reduce scratch

    const int t        = threadIdx.x;
    const int tid      = blockIdx.x * blockDim.x + t;
    const int nThreads = gridDim.x * blockDim.x;

    // ---- P0: zero histogram ----
    for (int i = tid; i < nNodes; i += nThreads) counts[i] = 0;
    grid.sync();

    // ---- P1: histogram (int4 reads) + fp16 convert ----
    {
        const int nE4 = nEdges >> 2;
        const int4* ed4 = (const int4*)edge_dst;
        for (int q = tid; q < nE4; q += nThreads) {
            const int4 d4 = ed4[q];
            atomicAdd(&counts[d4.x], 1);
            atomicAdd(&counts[d4.y], 1);
            atomicAdd(&counts[d4.z], 1);
            atomicAdd(&counts[d4.w], 1);
        }
        for (int e = (nE4 << 2) + tid; e < nEdges; e += nThreads)
            atomicAdd(&counts[edge_dst[e]], 1);
    }
    {
        const float4* x4 = (const float4*)x;
        uint2* xq = (uint2*)xh;
        const int nQ = nNodes * D / 4;
        for (int q = tid; q < nQ; q += nThreads) {
            const float4 v = x4[q];
            const __half2 lo = __floats2half2_rn(v.x, v.y);
            const __half2 hi = __floats2half2_rn(v.z, v.w);
            uint2 u;
            u.x = *(const unsigned*)&lo;
            u.y = *(const unsigned*)&hi;
            xq[q] = u;
        }
    }
    grid.sync();

    // ---- P2a: chunk sums ----
    const int nChunks = (nNodes + 255) / 256;
    for (int c = blockIdx.x; c < nChunks; c += gridDim.x) {
        const int i = c * 256 + t;
        sbuf[t] = (i < nNodes) ? counts[i] : 0;
        __syncthreads();
        for (int off = 128; off; off >>= 1) {
            if (t < off) sbuf[t] += sbuf[t + off];
            __syncthreads();
        }
        if (t == 0) chunkSum[c] = sbuf[0];
        __syncthreads();
    }
    grid.sync();

    // ---- P2b: chunk prefix + intra-chunk scan -> offsets, cursor ----
    for (int c = blockIdx.x; c < nChunks; c += gridDim.x) {
        int p = 0;
        for (int u = t; u < c; u += 256) p += chunkSum[u];
        sbuf[t] = p;
        __syncthreads();
        for (int off = 128; off; off >>= 1) {
            if (t < off) sbuf[t] += sbuf[t + off];
            __syncthreads();
        }
        const int prefix = sbuf[0];
        __syncthreads();

        const int i = c * 256 + t;
        const int v = (i < nNodes) ? counts[i] : 0;
        sbuf[t] = v;
        __syncthreads();
        for (int off = 1; off < 256; off <<= 1) {
            const int tv = (t >= off) ? sbuf[t - off] : 0;
            __syncthreads();
            sbuf[t] += tv;
            __syncthreads();
        }
        if (i < nNodes) {
            const int o = prefix + sbuf[t] - v;   // exclusive row start
            offsets[i] = o;
            cursor[i]  = o;
        }
        __syncthreads();
    }
    grid.sync();

    // ---- P3: scatter edges into dst bins; stage Wt while loads fly ----
    for (int e = tid; e < nEdges; e += nThreads) {
        const int d = edge_dst[e];
        const int pos = atomicAdd(&cursor[d], 1);
        sorted_sv[pos] = make_int2(edge_src[e], __float_as_int(edge_val[e]));
    }
    for (int i = t; i < D * D; i += 256) {
        const int k = i >> 6, j = i & 63;
        Wt[j][k] = W[i];
    }
    grid.sync();

    // ---- P4: gather + GEMV + norm + relu ----
    const int lane   = t & 63;
    const int w      = t >> 6;
    const int wave   = tid >> 6;
    const int nWaves = nThreads >> 6;

    for (int n = wave; n < nNodes; n += nWaves) {
        const int start = offsets[n];
        const int end   = cursor[n];            // == start + count after P3

        float a0 = 0.f, a1 = 0.f, a2 = 0.f, a3 = 0.f;
        int j = start;
        const int end4 = start + ((end - start) & ~3);
        for (; j < end4; j += 4) {
            const int2 e0 = sorted_sv[j + 0];
            const int2 e1 = sorted_sv[j + 1];
            const int2 e2 = sorted_sv[j + 2];
            const int2 e3 = sorted_sv[j + 3];
            a0 += __int_as_float(e0.y) * __half2float(xh[(size_t)e0.x * D + lane]);
            a1 += __int_as_float(e1.y) * __half2float(xh[(size_t)e1.x * D + lane]);
            a2 += __int_as_float(e2.y) * __half2float(xh[(size_t)e2.x * D + lane]);
            a3 += __int_as_float(e3.y) * __half2float(xh[(size_t)e3.x * D + lane]);
        }
        for (; j < end; ++j) {
            const int2 e = sorted_sv[j];
            a0 += __int_as_float(e.y) * __half2float(xh[(size_t)e.x * D + lane]);
        }
        const float acc = (a0 + a1) + (a2 + a3);

        accL[w][lane] = acc;

        float o = 0.f;
        #pragma unroll
        for (int k = 0; k < D; k += 4) {
            const float4 wv = *reinterpret_cast<const float4*>(&Wt[lane][k]);
            const float4 av = *reinterpret_cast<const float4*>(&accL[w][k]);
            o += av.x * wv.x + av.y * wv.y + av.z * wv.z + av.w * wv.w;
        }

        float ss = o * o;
        #pragma unroll
        for (int off = 32; off; off >>= 1)
            ss += __shfl_xor(ss, off, 64);
        const float inv = 1.f / fmaxf(sqrtf(ss), 1e-12f);

        out[(size_t)n * D + lane] = fmaxf(o * inv, 0.f);
    }
}

// ===========================================================================
// PATH B: fallback — round-5 multi-dispatch pipeline (verified: 296 us, pass)
// ===========================================================================
__global__ __launch_bounds__(256) void hist_convert_kernel(
    const int* __restrict__ edge_dst, int* __restrict__ counts, int nEdges,
    const float4* __restrict__ x4, uint2* __restrict__ xhq, int nQuads)
{
    const int tid    = blockIdx.x * blockDim.x + threadIdx.x;
    const int stride = gridDim.x * blockDim.x;
    for (int e = tid; e < nEdges; e += stride)
        atomicAdd(&counts[edge_dst[e]], 1);
    for (int q = tid; q < nQuads; q += stride) {
        const float4 v = x4[q];
        const __half2 lo = __floats2half2_rn(v.x, v.y);
        const __half2 hi = __floats2half2_rn(v.z, v.w);
        uint2 u;
        u.x = *reinterpret_cast<const unsigned*>(&lo);
        u.y = *reinterpret_cast<const unsigned*>(&hi);
        xhq[q] = u;
    }
}

__global__ __launch_bounds__(256) void scanA_kernel(
    const int* __restrict__ counts, int* __restrict__ incl,
    int* __restrict__ blockSums, int n)
{
    __shared__ int buf[256];
    const int i = blockIdx.x * 256 + threadIdx.x;
    int v = (i < n) ? counts[i] : 0;
    buf[threadIdx.x] = v;
    __syncthreads();
    for (int off = 1; off < 256; off <<= 1) {
        int t = (threadIdx.x >= off) ? buf[threadIdx.x - off] : 0;
        __syncthreads();
        buf[threadIdx.x] += t;
        __syncthreads();
    }
    if (i < n) incl[i] = buf[threadIdx.x];
    if (threadIdx.x == 255) blockSums[blockIdx.x] = buf[255];
}

__global__ __launch_bounds__(256) void scanC_kernel(
    const int* __restrict__ counts, const int* __restrict__ incl,
    const int* __restrict__ blockSums, int* __restrict__ offsets,
    int* __restrict__ cursor, int n)
{
    __shared__ int red[256];
    const int b = blockIdx.x;
    int p = 0;
    for (int t = threadIdx.x; t < b; t += 256) p += blockSums[t];
    red[threadIdx.x] = p;
    __syncthreads();
    for (int off = 128; off; off >>= 1) {
        if ((int)threadIdx.x < off) red[threadIdx.x] += red[threadIdx.x + off];
        __syncthreads();
    }
    const int prefix = red[0];
    const int i = b * 256 + (int)threadIdx.x;
    if (i < n) {
        const int off = incl[i] - counts[i] + prefix;
        offsets[i] = off;
        cursor[i]  = off;
    }
}

__global__ __launch_bounds__(256) void scatter_kernel(
    const int*   __restrict__ edge_src,
    const int*   __restrict__ edge_dst,
    const float* __restrict__ edge_val,
    int*  __restrict__ cursor,
    int2* __restrict__ sorted_sv,
    int nEdges)
{
    int i = blockIdx.x * blockDim.x + threadIdx.x;
    const int stride = gridDim.x * blockDim.x;
    for (; i < nEdges; i += stride) {
        const int d = edge_dst[i];
        const int pos = atomicAdd(&cursor[d], 1);
        sorted_sv[pos] = make_int2(edge_src[i], __float_as_int(edge_val[i]));
    }
}

__global__ __launch_bounds__(256) void gather_gemv_norm_kernel(
    const __half* __restrict__ xh,
    const float*  __restrict__ W,
    const int*    __restrict__ offsets,
    const int*    __restrict__ counts,
    const int2*   __restrict__ sorted_sv,
    float*        __restrict__ out,
    int nNodes)
{
    __shared__ float Wt[D][D + 4];
    __shared__ float accL[4][D];
    for (int i = threadIdx.x; i < D * D; i += blockDim.x) {
        const int k = i >> 6, j = i & 63;
        Wt[j][k] = W[i];
    }
    __syncthreads();

    const int lane   = threadIdx.x & 63;
    const int w      = threadIdx.x >> 6;
    const int wave   = (blockIdx.x * blockDim.x + threadIdx.x) >> 6;
    const int nWaves = (gridDim.x * blockDim.x) >> 6;

    for (int n = wave; n < nNodes; n += nWaves) {
        const int start = offsets[n];
        const int cnt   = counts[n];

        float a0 = 0.f, a1 = 0.f, a2 = 0.f, a3 = 0.f;
        int j = start;
        const int end4 = start + (cnt & ~3);
        for (; j < end4; j += 4) {
            const int2 e0 = sorted_sv[j + 0];
            const int2 e1 = sorted_sv[j + 1];
            const int2 e2 = sorted_sv[j + 2];
            const int2 e3 = sorted_sv[j + 3];
            a0 += __int_as_float(e0.y) * __half2float(xh[(size_t)e0.x * D + lane]);
            a1 += __int_as_float(e1.y) * __half2float(xh[(size_t)e1.x * D + lane]);
            a2 += __int_as_float(e2.y) * __half2float(xh[(size_t)e2.x * D + lane]);
            a3 += __int_as_float(e3.y) * __half2float(xh[(size_t)e3.x * D + lane]);
        }
        const int end = start + cnt;
        for (; j < end; ++j) {
            const int2 e = sorted_sv[j];
            a0 += __int_as_float(e.y) * __half2float(xh[(size_t)e.x * D + lane]);
        }
        const float acc = (a0 + a1) + (a2 + a3);

        accL[w][lane] = acc;

        float o = 0.f;
        #pragma unroll
        for (int k = 0; k < D; k += 4) {
            const float4 wv = *reinterpret_cast<const float4*>(&Wt[lane][k]);
            const float4 av = *reinterpret_cast<const float4*>(&accL[w][k]);
            o += av.x * wv.x + av.y * wv.y + av.z * wv.z + av.w * wv.w;
        }

        float ss = o * o;
        #pragma unroll
        for (int off = 32; off; off >>= 1)
            ss += __shfl_xor(ss, off, 64);
        const float inv = 1.f / fmaxf(sqrtf(ss), 1e-12f);

        out[(size_t)n * D + lane] = fmaxf(o * inv, 0.f);
    }
}

// ===========================================================================
extern "C" void kernel_launch(void* const* d_in, const int* in_sizes, int n_in,
                              void* d_out, int out_size, void* d_ws, size_t ws_size,
                              hipStream_t stream)
{
    const float* x        = (const float*)d_in[0];
    const float* edge_val = (const float*)d_in[1];
    const float* weight   = (const float*)d_in[2];
    const int*   edge_src = (const int*)d_in[3];
    const int*   edge_dst = (const int*)d_in[4];

    int nNodes = in_sizes[0] / D;
    int nEdges = in_sizes[1];
    const int nB = (nNodes + 255) / 256;

    // unified workspace layout (superset of both paths)
    int*    counts    = (int*)d_ws;                    // [nNodes]
    int*    offsets   = counts  + nNodes;              // [nNodes]
    int*    cursor    = offsets + nNodes;              // [nNodes]
    int*    incl      = cursor  + nNodes;              // [nNodes]   (fallback only)
    int*    chunkSum  = incl    + nNodes;              // [<=4096]
    int2*   sorted_sv = (int2*)(chunkSum + 4096);      // [nEdges]
    __half* xh        = (__half*)(sorted_sv + nEdges); // [nNodes*D]
    float*  out       = (float*)d_out;

    // --- try PATH A: cooperative, grid sized from occupancy query ---
    bool coopDone = false;
    int blocksPerCU = 0, nCU = 0, dev = 0;
    (void)hipGetDevice(&dev);
    hipError_t eo = hipOccupancyMaxActiveBlocksPerMultiprocessor(
        &blocksPerCU, fused_graphconv_kernel, 256, 0);
    hipError_t ec = hipDeviceGetAttribute(
        &nCU, hipDeviceAttributeMultiprocessorCount, dev);

    if (eo == hipSuccess && ec == hipSuccess && blocksPerCU > 0 && nCU > 0) {
        int grid = blocksPerCU * nCU;
        if (grid > 1024) grid = 1024;
        if (grid >= 64) {
            void* kargs[] = {
                (void*)&x, (void*)&edge_val, (void*)&weight,
                (void*)&edge_src, (void*)&edge_dst,
                (void*)&counts, (void*)&offsets, (void*)&cursor, (void*)&chunkSum,
                (void*)&sorted_sv, (void*)&xh, (void*)&out,
                (void*)&nNodes, (void*)&nEdges
            };
            hipError_t le = hipLaunchCooperativeKernel(
                (const void*)fused_graphconv_kernel,
                dim3(grid), dim3(256), kargs, 0, stream);
            coopDone = (le == hipSuccess);
        }
    }

    // --- PATH B fallback: proven multi-dispatch pipeline ---
    if (!coopDone) {
        (void)hipMemsetAsync(counts, 0, (size_t)nNodes * sizeof(int), stream);
        hist_convert_kernel<<<2048, 256, 0, stream>>>(
            edge_dst, counts, nEdges, (const float4*)x, (uint2*)xh, nNodes * D / 4);
        scanA_kernel<<<nB, 256, 0, stream>>>(counts, incl, chunkSum, nNodes);
        scanC_kernel<<<nB, 256, 0, stream>>>(counts, incl, chunkSum, offsets, cursor, nNodes);
        scatter_kernel<<<4096, 256, 0, stream>>>(
            edge_src, edge_dst, edge_val, cursor, sorted_sv, nEdges);
        gather_gemv_norm_kernel<<<2048, 256, 0, stream>>>(
            xh, weight, offsets, counts, sorted_sv, out, nNodes);
    }
}